// Round 1
// 95.555 us; speedup vs baseline: 1.0195x; 1.0195x over previous
//
#include <hip/hip_runtime.h>
#include <hip/hip_bf16.h>

typedef __bf16 bf16x8 __attribute__((ext_vector_type(8)));
typedef float f32x16 __attribute__((ext_vector_type(16)));
typedef unsigned int u32x4 __attribute__((ext_vector_type(4)));
typedef unsigned short u16;

// Problem constants: T=16, N=128, D=512, M=4096, NT=2048, TEMP=0.1
// ws layout: zn bf16[4096*512] (4 MiB) | expsum f32[4096] | possum f32[4096]

// ---------------------------------------------------------------- normalize
__global__ void nrm_kernel(const float* __restrict__ z, u16* __restrict__ zn,
                           float* __restrict__ expsum, float* __restrict__ possum) {
    int row = blockIdx.x;          // 4096 rows
    int tid = threadIdx.x;         // 128 threads, 4 floats each
    float4 v = ((const float4*)(z + row * 512))[tid];
    float ss = v.x * v.x + v.y * v.y + v.z * v.z + v.w * v.w;
#pragma unroll
    for (int off = 32; off; off >>= 1) ss += __shfl_down(ss, off, 64);
    __shared__ float red[2];
    if ((tid & 63) == 0) red[tid >> 6] = ss;
    __syncthreads();
    float norm = fmaxf(sqrtf(red[0] + red[1]), 1e-8f);  // matches ref clamp
    float sc = 1.0f / norm;
    __hip_bfloat16 b[4];
    b[0] = __float2bfloat16(v.x * sc);
    b[1] = __float2bfloat16(v.y * sc);
    b[2] = __float2bfloat16(v.z * sc);
    b[3] = __float2bfloat16(v.w * sc);
    uint2 p;
    __builtin_memcpy(&p, b, 8);
    ((uint2*)(zn + row * 512))[tid] = p;
    if (tid == 0) { expsum[row] = 0.f; possum[row] = 0.f; }
}

// ------------------------------------------------- symmetric GEMM (+pos tail)
// Blocks [0,528): triangular (ti<=tj) 128x128 tiles of the symmetric Gram.
//   4 waves/WG, wave owns 32 rows with A (32x512 bf16) resident in 128 VGPRs.
//   Col tiles of 32 staged in LDS, XOR-swizzled 16B granules (conflict-free
//   ds_read_b128), double-buffered: one barrier per col-tile, next tile's
//   global loads issued before the MFMA cluster (latency hidden under MFMA).
//   Off-diag tiles: e_ij accumulated into expsum[i] (row reduce at end) AND
//   expsum[j] (col partial atomics, symmetry). Diag tiles: rows only, mask
//   the true diagonal in the aligned (wave==ct) sub-block.
// Blocks [528,656): pos work — 32x32 group Gram, possum[i] = 10*sum dot.
__global__ __launch_bounds__(256, 2) void gemm_kernel(const u16* __restrict__ zn,
                                                      float* __restrict__ expsum,
                                                      float* __restrict__ possum) {
    if (blockIdx.x >= 528) {       // ---------------- positives tail
        if (threadIdx.x < 64) {
            int g = blockIdx.x - 528;
            int l = threadIdx.x;
            int u = l & 31, h2 = l >> 5;
            int grow = (u < 16) ? (g * 16 + u) : (2048 + g * 16 + (u - 16));
            const u32x4* src = (const u32x4*)(zn + grow * 512);
            f32x16 acc = {};
#pragma unroll
            for (int kc = 0; kc < 32; ++kc) {
                bf16x8 f = __builtin_bit_cast(bf16x8, src[h2 + 2 * kc]);
                acc = __builtin_amdgcn_mfma_f32_32x32x16_bf16(f, f, acc, 0, 0, 0);
            }
#pragma unroll
            for (int r = 0; r < 16; ++r) {
                int rrow = (r & 3) + 8 * (r >> 2) + 4 * h2;
                float v = (rrow == u) ? 0.f : acc[r];
                v += __shfl_xor(v, 1, 64);
                v += __shfl_xor(v, 2, 64);
                v += __shfl_xor(v, 4, 64);
                v += __shfl_xor(v, 8, 64);
                v += __shfl_xor(v, 16, 64);
                if (u == 0) {
                    int gr = (rrow < 16) ? (g * 16 + rrow) : (2048 + g * 16 + (rrow - 16));
                    possum[gr] = v * 10.0f;
                }
            }
        }
        return;
    }

    __shared__ u16 Bt[2][32 * 512];            // 64 KiB double buffer

    // triangular decode: tile row ti has 32-ti tiles (tj = ti..31)
    int b = blockIdx.x;
    int ti = 0;
    while (b >= 32 - ti) { b -= 32 - ti; ++ti; }
    int tj = ti + b;

    int wave = threadIdx.x >> 6;
    int l = threadIdx.x & 63;
    int m = l & 31, h = l >> 5;
    int rowbase = ti * 128 + wave * 32;
    int colbase = tj * 128;
    bool diag = (ti == tj);

    // A fragments, full K=512: row rowbase+m, k-granule h+2*kc
    u32x4 a[32];
    const u32x4* arow = (const u32x4*)(zn + (rowbase + m) * 512);
#pragma unroll
    for (int kc = 0; kc < 32; ++kc) a[kc] = arow[h + 2 * kc];

    float racc[16];
#pragma unroll
    for (int r = 0; r < 16; ++r) racc[r] = 0.f;

    // staging geometry: thread -> (col c, granule phase g0); LDS granule index
    // within a col is XOR-swizzled by (c&7) so col-major b128 reads are
    // conflict-free (content at linear granule gi is original granule gi^(c&7)).
    int c = threadIdx.x >> 3;
    int g0 = threadIdx.x & 7;
    int woff = c * 64 + (g0 ^ (c & 7));        // 16B-granule index in buffer
    const u16* zsrc = zn + (colbase + c) * 512;

    u32x4 stg[8];
    {   // prologue: stage col-tile 0 into Bt[0]
        const u32x4* src = (const u32x4*)zsrc;
#pragma unroll
        for (int i = 0; i < 8; ++i) stg[i] = src[g0 + 8 * i];
        u32x4* dst = ((u32x4*)Bt[0]) + woff;
#pragma unroll
        for (int i = 0; i < 8; ++i) dst[8 * i] = stg[i];
    }

    // read geometry: desired granule (h+2kc)^(m&7), kc = 4*kg+q decomposes to
    // byte addr = m*1024 + (h^sw0)*16 + (q^sw12)*32 + kg*128  -> 4 base
    // pointers + compile-time kg offsets, zero per-read VALU.
    int sw0 = m & 1, sw12 = (m >> 1) & 3;
    int rbyte[4];
#pragma unroll
    for (int q = 0; q < 4; ++q)
        rbyte[q] = m * 1024 + (h ^ sw0) * 16 + ((q ^ sw12) * 32);

    const char* rb = (const char*)Bt[0];
    char* wb = (char*)Bt[1];
    __syncthreads();

    for (int ct = 0; ct < 4; ++ct) {
        if (ct < 3) {   // issue next tile's global loads early (hide under MFMA)
            const u32x4* src = (const u32x4*)(zsrc + (ct + 1) * 32 * 512);
#pragma unroll
            for (int i = 0; i < 8; ++i) stg[i] = src[g0 + 8 * i];
        }
        f32x16 acc = {};
        __builtin_amdgcn_s_setprio(1);
#pragma unroll
        for (int kg = 0; kg < 8; ++kg) {
#pragma unroll
            for (int q = 0; q < 4; ++q) {
                bf16x8 bf = *(const bf16x8*)(rb + rbyte[q] + kg * 128);
                acc = __builtin_amdgcn_mfma_f32_32x32x16_bf16(
                    __builtin_bit_cast(bf16x8, a[4 * kg + q]), bf, acc, 0, 0, 0);
            }
        }
        __builtin_amdgcn_s_setprio(0);

        if (diag && ct == wave) {  // aligned sub-block: mask true diagonal, rows only
#pragma unroll
            for (int r = 0; r < 16; ++r) {
                int rrow = (r & 3) + 8 * (r >> 2) + 4 * h;
                if (rrow != m) racc[r] += __builtin_exp2f(acc[r] * 14.426950408889634f);
            }
        } else {
            float csum = 0.f;
#pragma unroll
            for (int r = 0; r < 16; ++r) {
                float e = __builtin_exp2f(acc[r] * 14.426950408889634f);
                racc[r] += e;
                csum += e;
            }
            if (!diag) {           // symmetric contribution to the col rows
                csum += __shfl_xor(csum, 32, 64);   // combine the two k-halves
                if (h == 0) atomicAdd(&expsum[colbase + ct * 32 + m], csum);
            }
        }

        if (ct < 3) {   // write staged tile into the other buffer
            u32x4* dst = ((u32x4*)wb) + woff;
#pragma unroll
            for (int i = 0; i < 8; ++i) dst[8 * i] = stg[i];
        }
        __syncthreads();           // staged buffer visible; prev reads all done
        const char* t = rb; rb = (const char*)wb; wb = (char*)t;
    }

    // row sums: reduce over the 32 cols held in lanes of each half
#pragma unroll
    for (int r = 0; r < 16; ++r) {
        float v = racc[r];
        v += __shfl_xor(v, 1, 64);
        v += __shfl_xor(v, 2, 64);
        v += __shfl_xor(v, 4, 64);
        v += __shfl_xor(v, 8, 64);
        v += __shfl_xor(v, 16, 64);
        if (m == 0) {
            int rrow = (r & 3) + 8 * (r >> 2) + 4 * h;
            atomicAdd(&expsum[rowbase + rrow], v);
        }
    }
}

// ---------------------------------------------------------------- finalize
__global__ void fin_kernel(const float* __restrict__ expsum,
                           const float* __restrict__ possum, float* __restrict__ out) {
    int tid = threadIdx.x;         // 1024
    float s = 0.f;
    for (int i = tid; i < 4096; i += 1024)
        s += __logf(expsum[i]) - possum[i] * (1.0f / 31.0f);
#pragma unroll
    for (int off = 32; off; off >>= 1) s += __shfl_down(s, off, 64);
    __shared__ float red[16];
    if ((tid & 63) == 0) red[tid >> 6] = s;
    __syncthreads();
    if (tid == 0) {
        float t = 0.f;
#pragma unroll
        for (int i = 0; i < 16; ++i) t += red[i];
        out[0] = t * (1.0f / 4096.0f);
    }
}

extern "C" void kernel_launch(void* const* d_in, const int* in_sizes, int n_in,
                              void* d_out, int out_size, void* d_ws, size_t ws_size,
                              hipStream_t stream) {
    const float* z = (const float*)d_in[0];
    // d_in[1] (done) is provably dead: positive_mask reduces to block-diag + eye.
    u16* zn = (u16*)d_ws;
    float* expsum = (float*)((char*)d_ws + (4u << 20));
    float* possum = expsum + 4096;
    float* out = (float*)d_out;

    nrm_kernel<<<4096, 128, 0, stream>>>(z, zn, expsum, possum);
    gemm_kernel<<<656, 256, 0, stream>>>(zn, expsum, possum);  // 528 sym tiles + 128 pos
    fin_kernel<<<1, 1024, 0, stream>>>(expsum, possum, out);
}